// Round 19
// baseline (149.791 us; speedup 1.0000x reference)
//
#include <hip/hip_runtime.h>

typedef _Float16 f16;
typedef _Float16 f16x2 __attribute__((ext_vector_type(2)));
typedef _Float16 f16x4 __attribute__((ext_vector_type(4)));
typedef _Float16 f16x8 __attribute__((ext_vector_type(8)));
typedef __fp16   h16x2 __attribute__((ext_vector_type(2)));
typedef float    f32x4 __attribute__((ext_vector_type(4)));
typedef float    f32x16 __attribute__((ext_vector_type(16)));

static constexpr float L2E = 1.44269504088896340736f;
// folded into q-projection: (1/sqrt(64)) * log2(e)
static constexpr float QSC = 0.18033688011112042f;

static __device__ __forceinline__ f32x4 mfma16(f16x8 a, f16x8 b, f32x4 c) {
    return __builtin_amdgcn_mfma_f32_16x16x32_f16(a, b, c, 0, 0, 0);
}
static __device__ __forceinline__ f32x16 mfma32(f16x8 a, f16x8 b, f32x16 c) {
    return __builtin_amdgcn_mfma_f32_32x32x16_f16(a, b, c, 0, 0, 0);
}
static __device__ __forceinline__ f16x2 cvt_pk(float a, float b) {
    h16x2 t = __builtin_amdgcn_cvt_pkrtz(a, b);
    return __builtin_bit_cast(f16x2, t);
}
// async global->LDS DMA, 16B per lane. LDS dest = WAVE-UNIFORM base + lane*16.
static __device__ __forceinline__ void gload16(const void* g, void* l) {
    __builtin_amdgcn_global_load_lds(
        (const __attribute__((address_space(1))) unsigned int*)g,
        (__attribute__((address_space(3))) unsigned int*)l, 16, 0, 0);
}

// ---------------------------------------------------------------------------
// Kernel 0: transpose W [512][64] f32 -> WT [64][512] f16 (per tensor)
// ---------------------------------------------------------------------------
__global__ void ah_wt_prep(const float* __restrict__ Wq,
                           const float* __restrict__ Wk,
                           const float* __restrict__ Wv,
                           f16* __restrict__ WT) {
    const float* W = (blockIdx.x == 0) ? Wq : (blockIdx.x == 1) ? Wk : Wv;
    f16* o = WT + (size_t)blockIdx.x * (64 * 512);
    for (int i = threadIdx.x; i < 64 * 512; i += blockDim.x) {
        int col = i >> 9, e = i & 511;
        o[i] = (f16)W[e * 64 + col];
    }
}

// ---------------------------------------------------------------------------
// Kernel 1: projection  P = X @ W + b  (X fp32 [32768][512] -> out f16).
// MAX-TLP STREAMING variant: every prior structure ran <=12-16 waves/CU
// (grid- or LDS-limited) and pinned at ~2.6-3.2 TB/s; m13's 6.3 TB/s copy
// runs ~32 waves/CU. So: BM=32, block=128 (2 waves x 16 rows), grid
// (1024,3)=3072 blocks -> 12 resident blocks/CU = 24 waves/CU.
// __launch_bounds__(128,8) caps VGPR<=64. NO main-loop LDS (4.3KB epilogue
// only). X via plain float4 loads; W fragments from global (L2-hot 96KB).
// tensor 0 -> qp (scaled QSC), 1 -> kp, 2 -> vpT [b][64][4096]
// ---------------------------------------------------------------------------
__global__ __launch_bounds__(128, 8) void ah_proj(
    const float* __restrict__ Xq, const float* __restrict__ Xk, const float* __restrict__ Xv,
    const float* __restrict__ bq, const float* __restrict__ bk, const float* __restrict__ bv,
    const f16* __restrict__ WT,
    f16* __restrict__ qp, f16* __restrict__ kp, f16* __restrict__ vpT) {

    const int tens = blockIdx.y;
    const float* X    = (tens == 0) ? Xq : (tens == 1) ? Xk : Xv;
    const float* bias = (tens == 0) ? bq : (tens == 1) ? bk : bv;
    const f16* wt = WT + (size_t)tens * (64 * 512);
    const float osc = (tens == 0) ? QSC : 1.0f;

    const int lane = threadIdx.x & 63;
    const int wave = threadIdx.x >> 6;            // 0..1
    const int l15 = lane & 15, g = lane >> 4;
    const int row0 = blockIdx.x * 32;
    const int wrow = wave * 16;

    f32x4 acc[4];
#pragma unroll
    for (int b = 0; b < 4; ++b) acc[b] = (f32x4){0.f, 0.f, 0.f, 0.f};

    const float* xrow = X + (size_t)(row0 + wrow + l15) * 512;

#pragma unroll 4
    for (int ec = 0; ec < 16; ++ec) {             // K = 512 in chunks of 32
        const float* px = xrow + ec * 32 + g * 8;
        float4 v0 = *(const float4*)px;
        float4 v1 = *(const float4*)(px + 4);
        f16x2 p0 = cvt_pk(v0.x, v0.y), p1 = cvt_pk(v0.z, v0.w);
        f16x2 p2 = cvt_pk(v1.x, v1.y), p3 = cvt_pk(v1.z, v1.w);
        f16x8 a;
        a[0] = p0[0]; a[1] = p0[1]; a[2] = p1[0]; a[3] = p1[1];
        a[4] = p2[0]; a[5] = p2[1]; a[6] = p3[0]; a[7] = p3[1];
#pragma unroll
        for (int cf = 0; cf < 4; ++cf) {
            f16x8 bfr = *(const f16x8*)(wt + (size_t)(cf * 16 + l15) * 512 + ec * 32 + g * 8);
            acc[cf] = mfma16(a, bfr, acc[cf]);
        }
    }

    // epilogue: bias (+ scale for qp) + f16, stage in small LDS [32][68]
    __shared__ __align__(16) f16 lds[32 * 68];
#pragma unroll
    for (int cf = 0; cf < 4; ++cf) {
        float b = bias[cf * 16 + l15];
#pragma unroll
        for (int r = 0; r < 4; ++r) {
            int rr = wrow + g * 4 + r;            // C layout: row=(l>>4)*4+r
            lds[rr * 68 + cf * 16 + l15] = (f16)((acc[cf][r] + b) * osc);
        }
    }
    __syncthreads();

    if (tens < 2) {
        f16* o = ((tens == 0) ? qp : kp) + (size_t)row0 * 64;
        for (int c = threadIdx.x; c < 32 * 16; c += 128) {   // 8B chunks
            int r = c >> 4, ch = c & 15;
            *(f16x4*)(o + r * 64 + ch * 4) = *(const f16x4*)(&lds[r * 68 + ch * 4]);
        }
    } else {
        int b = row0 >> 12, n0 = row0 & 4095;
        f16* o = vpT + (size_t)b * 64 * 4096 + n0;
        for (int c = threadIdx.x; c < 64 * 8; c += 128) {    // 64 d x 8 chunks of 4 n
            int d = c >> 3, nch = c & 7;
            f16x4 v;
#pragma unroll
            for (int j = 0; j < 4; ++j) v[j] = lds[(nch * 4 + j) * 68 + d];
            *(f16x4*)(o + (size_t)d * 4096 + nch * 4) = v;
        }
    }
}

// ---------------------------------------------------------------------------
// Kernel 2: fused flash attention. [R18 verbatim] 4-DEEP staging ring,
// ONE barrier per iteration: vmcnt(8) -> compute(buf i&3) -> s_barrier ->
// stage(buf (i+3)&3). LDS [4 s][4 buf][K 4KB | V 4KB] = 128KB, 1 block/CU.
// V tile unit-major (conflict-minimal); K XOR-swizzled (validated).
// grid 256: batch = id&7 (XCD-pinned), qtile = id>>3 (128 q-rows).
// block 512 = 8 waves = 2 qg (64 q) x 4 keysplit s (1024 keys, 32 iters of 32).
// ---------------------------------------------------------------------------
__global__ __launch_bounds__(512, 1) void ah_attn(
    const f16* __restrict__ qp, const f16* __restrict__ kp, const f16* __restrict__ vpT,
    const int* __restrict__ maskp, float* __restrict__ out) {

    const int id = blockIdx.x;
    const int batch = id & 7, qtile = id >> 3;
    const int lane = threadIdx.x & 63, wave = threadIdx.x >> 6;
    const int l31 = lane & 31, hi2 = lane >> 5;
    const int s = wave & 3, qg = wave >> 2;
    const int q0 = qtile * 128 + qg * 64;
    const float mthr = L2E * (float)maskp[0];

    const f16* qpb = qp + (size_t)batch * 4096 * 64;
    const f16* kpb = kp + (size_t)batch * 4096 * 64;
    const f16* vpb = vpT + (size_t)batch * 64 * 4096;

    __shared__ __align__(16) char smem[131072];    // [4 s][4 buf][8KB]
    __shared__ float mlx[2][4][2][32];

    const int krow = lane >> 3;                    // 0..7
    const int eswzK = (lane & 7) ^ krow;           // source col16 swizzle (K)
    const int swzK = l31 & 7;                      // read-side XOR (K)

#define STAGE(BUF, IT) do {                                                         \
    const int _k0 = (((IT) * 4 + s) << 5);                                          \
    char* _b = smem + (s * 4 + (BUF)) * 8192 + (qg ? 4096 : 0);                     \
    if (qg == 0) {                                                                  \
        _Pragma("unroll")                                                           \
        for (int _j = 0; _j < 4; ++_j)                                              \
            gload16(kpb + (size_t)(_k0 + _j * 8 + krow) * 64 + eswzK * 8,           \
                    _b + _j * 1024);                                                \
    } else {                                                                        \
        _Pragma("unroll")                                                           \
        for (int _j = 0; _j < 4; ++_j)                                              \
            gload16(vpb + (size_t)(_j * 16 + (lane & 15)) * 4096 + _k0 +            \
                        (lane >> 4) * 8,                                            \
                    _b + _j * 1024);                                                \
    }                                                                               \
} while (0)

    f16x8 qf_[2][4];
#pragma unroll
    for (int qt = 0; qt < 2; ++qt)
#pragma unroll
        for (int st = 0; st < 4; ++st)
            qf_[qt][st] = *(const f16x8*)(qpb + (size_t)(q0 + qt * 32 + l31) * 64 + st * 16 + hi2 * 8);

    f32x16 oacc[2][2];
#pragma unroll
    for (int dt = 0; dt < 2; ++dt)
#pragma unroll
        for (int qt = 0; qt < 2; ++qt)
#pragma unroll
            for (int r = 0; r < 16; ++r) oacc[dt][qt][r] = 0.f;
    float ps[2] = {0.f, 0.f};

    STAGE(0, 0); STAGE(1, 1); STAGE(2, 2);
    __builtin_amdgcn_s_barrier();                 // stages issued before loop
    for (int it = 0; it < 32; ++it) {
        if (it < 30)      asm volatile("s_waitcnt vmcnt(8)" ::: "memory");
        else if (it == 30) asm volatile("s_waitcnt vmcnt(4)" ::: "memory");
        else              asm volatile("s_waitcnt vmcnt(0)" ::: "memory");
        __builtin_amdgcn_sched_barrier(0);

        const char* kb = smem + (s * 4 + (it & 3)) * 8192;
        const char* vb = kb + 4096;

        // ---- K frags + QK^T ----
        f16x8 ka[4];
#pragma unroll
        for (int st = 0; st < 4; ++st)
            ka[st] = *(const f16x8*)(kb + l31 * 128 + (((st * 2 + hi2) ^ swzK) << 4));
        f32x16 sacc[2];
#pragma unroll
        for (int qt = 0; qt < 2; ++qt)
#pragma unroll
            for (int r = 0; r < 16; ++r) sacc[qt][r] = 0.f;
#pragma unroll
        for (int st = 0; st < 4; ++st)
#pragma unroll
            for (int qt = 0; qt < 2; ++qt)
                sacc[qt] = mfma32(ka[st], qf_[qt][st], sacc[qt]);

        // ---- V frags (unit-major layout) ----
        f16x8 av[2][2];
#pragma unroll
        for (int dt = 0; dt < 2; ++dt) {
            const char* vchunk = vb + (dt * 2 + (l31 >> 4)) * 1024 + (l31 & 15) * 16 + hi2 * 8;
#pragma unroll
            for (int t = 0; t < 2; ++t) {
                *(f16x4*)(&av[dt][t])       = *(const f16x4*)(vchunk + (t * 2 + 0) * 256);
                *((f16x4*)(&av[dt][t]) + 1) = *(const f16x4*)(vchunk + (t * 2 + 1) * 256);
            }
        }

        // ---- fixed-max softmax: p = exp2(sacc), pack pairs -> PV B-frags ----
        f16x8 pb_[2][2];
#pragma unroll
        for (int qt = 0; qt < 2; ++qt)
#pragma unroll
            for (int t = 0; t < 2; ++t)
#pragma unroll
                for (int w = 0; w < 4; ++w) {
                    float s0 = sacc[qt][t * 8 + 2 * w];
                    float s1 = sacc[qt][t * 8 + 2 * w + 1];
                    float e0 = __builtin_amdgcn_exp2f(s0);
                    float e1 = __builtin_amdgcn_exp2f(s1);
                    float p0 = (s0 == mthr) ? 0.f : e0;
                    float p1 = (s1 == mthr) ? 0.f : e1;
                    ps[qt] += p0 + p1;
                    ((f16x2*)(&pb_[qt][t]))[w] = cvt_pk(p0, p1);
                }

        // ---- PV ----
#pragma unroll
        for (int dt = 0; dt < 2; ++dt)
#pragma unroll
            for (int qt = 0; qt < 2; ++qt)
#pragma unroll
                for (int t = 0; t < 2; ++t)
                    oacc[dt][qt] = mfma32(av[dt][t], pb_[qt][t], oacc[dt][qt]);

        __builtin_amdgcn_sched_barrier(0);
        __builtin_amdgcn_s_barrier();             // all waves done with buf (it-1)&3
        __builtin_amdgcn_sched_barrier(0);
        if (it < 29) STAGE((it + 3) & 3, it + 3); // overwrite is now safe
    }
#undef STAGE

    // ---- epilogue: Sum(p) exchange + 4-way tree combine in recycled LDS ----
    ps[0] += __shfl_xor(ps[0], 32);
    ps[1] += __shfl_xor(ps[1], 32);
    if (lane < 32) { mlx[qg][s][0][lane] = ps[0]; mlx[qg][s][1][lane] = ps[1]; }
    __syncthreads();

    float* SC = (float*)smem;        // [qg*2+b][64 regs][64 lanes]
#define SCI(B, DT, QT, R) ((((qg * 2 + (B)) * 64) + ((DT) * 2 + (QT)) * 16 + (R)) * 64 + lane)
    if (s >= 2) {
#pragma unroll
        for (int dt = 0; dt < 2; ++dt)
#pragma unroll
            for (int qt = 0; qt < 2; ++qt)
#pragma unroll
                for (int r = 0; r < 16; ++r)
                    SC[SCI(s - 2, dt, qt, r)] = oacc[dt][qt][r];
    }
    __syncthreads();
    if (s < 2) {
#pragma unroll
        for (int dt = 0; dt < 2; ++dt)
#pragma unroll
            for (int qt = 0; qt < 2; ++qt)
#pragma unroll
                for (int r = 0; r < 16; ++r)
                    oacc[dt][qt][r] += SC[SCI(s, dt, qt, r)];
        if (s == 1) {
#pragma unroll
            for (int dt = 0; dt < 2; ++dt)
#pragma unroll
                for (int qt = 0; qt < 2; ++qt)
#pragma unroll
                    for (int r = 0; r < 16; ++r)
                        SC[SCI(1, dt, qt, r)] = oacc[dt][qt][r];
        }
    }
    __syncthreads();
    if (s == 0) {
        float inv[2];
#pragma unroll
        for (int qt = 0; qt < 2; ++qt)
            inv[qt] = 1.0f / (mlx[qg][0][qt][l31] + mlx[qg][1][qt][l31] +
                              mlx[qg][2][qt][l31] + mlx[qg][3][qt][l31]);
#pragma unroll
        for (int qt = 0; qt < 2; ++qt) {
            float* o0 = out + ((size_t)batch * 4096 + q0 + qt * 32 + l31) * 64;
#pragma unroll
            for (int dt = 0; dt < 2; ++dt)
#pragma unroll
                for (int rg = 0; rg < 4; ++rg) {  // reg r=rg*4+j -> d = dt*32+rg*8+hi*4+j
                    float4 v;
                    v.x = (oacc[dt][qt][rg * 4 + 0] + SC[SCI(1, dt, qt, rg * 4 + 0)]) * inv[qt];
                    v.y = (oacc[dt][qt][rg * 4 + 1] + SC[SCI(1, dt, qt, rg * 4 + 1)]) * inv[qt];
                    v.z = (oacc[dt][qt][rg * 4 + 2] + SC[SCI(1, dt, qt, rg * 4 + 2)]) * inv[qt];
                    v.w = (oacc[dt][qt][rg * 4 + 3] + SC[SCI(1, dt, qt, rg * 4 + 3)]) * inv[qt];
                    *(float4*)(o0 + dt * 32 + rg * 8 + hi2 * 4) = v;
                }
        }
    }
#undef SCI
}

// ---------------------------------------------------------------------------
extern "C" void kernel_launch(void* const* d_in, const int* in_sizes, int n_in,
                              void* d_out, int out_size, void* d_ws, size_t ws_size,
                              hipStream_t stream) {
    const float* q  = (const float*)d_in[0];
    const float* k  = (const float*)d_in[1];
    const float* v  = (const float*)d_in[2];
    const float* Wq = (const float*)d_in[3];
    const float* bq = (const float*)d_in[4];
    const float* Wk = (const float*)d_in[5];
    const float* bk = (const float*)d_in[6];
    const float* Wv = (const float*)d_in[7];
    const float* bv = (const float*)d_in[8];
    const int* mask = (const int*)d_in[9];
    float* out = (float*)d_out;

    const size_t NTOK = (size_t)8 * 4096;      // 32768 rows
    f16* qp  = (f16*)d_ws;                     // [8][4096][64]  (pre-scaled by QSC)
    f16* kp  = qp + NTOK * 64;                 // [8][4096][64]
    f16* vpT = kp + NTOK * 64;                 // [8][64][4096]
    f16* WT  = vpT + NTOK * 64;                // [3][64][512]

    ah_wt_prep<<<dim3(3), 256, 0, stream>>>(Wq, Wk, Wv, WT);
    ah_proj<<<dim3(1024, 3), 128, 0, stream>>>(q, k, v, bq, bk, bv, WT, qp, kp, vpT);
    ah_attn<<<dim3(256), 512, 0, stream>>>(qp, kp, vpT, mask, out);
}

// Round 20
// 123.035 us; speedup vs baseline: 1.2175x; 1.2175x over previous
//
#include <hip/hip_runtime.h>

typedef _Float16 f16;
typedef _Float16 f16x2 __attribute__((ext_vector_type(2)));
typedef _Float16 f16x4 __attribute__((ext_vector_type(4)));
typedef _Float16 f16x8 __attribute__((ext_vector_type(8)));
typedef __fp16   h16x2 __attribute__((ext_vector_type(2)));
typedef float    f32x4 __attribute__((ext_vector_type(4)));
typedef float    f32x16 __attribute__((ext_vector_type(16)));

static constexpr float L2E = 1.44269504088896340736f;
// folded into q-projection: (1/sqrt(64)) * log2(e)
static constexpr float QSC = 0.18033688011112042f;

static __device__ __forceinline__ f32x4 mfma16(f16x8 a, f16x8 b, f32x4 c) {
    return __builtin_amdgcn_mfma_f32_16x16x32_f16(a, b, c, 0, 0, 0);
}
static __device__ __forceinline__ f32x16 mfma32(f16x8 a, f16x8 b, f32x16 c) {
    return __builtin_amdgcn_mfma_f32_32x32x16_f16(a, b, c, 0, 0, 0);
}
static __device__ __forceinline__ f16x2 cvt_pk(float a, float b) {
    h16x2 t = __builtin_amdgcn_cvt_pkrtz(a, b);
    return __builtin_bit_cast(f16x2, t);
}
// async global->LDS DMA, 16B per lane. LDS dest = WAVE-UNIFORM base + lane*16;
// global source is PER-LANE (pass base + lane-dependent offset).
static __device__ __forceinline__ void gload16(const void* g, void* l) {
    __builtin_amdgcn_global_load_lds(
        (const __attribute__((address_space(1))) unsigned int*)g,
        (__attribute__((address_space(3))) unsigned int*)l, 16, 0, 0);
}

// ---------------------------------------------------------------------------
// Kernel 0: transpose W [512][64] f32 -> WT [64][512] f16 (per tensor)
// ---------------------------------------------------------------------------
__global__ void ah_wt_prep(const float* __restrict__ Wq,
                           const float* __restrict__ Wk,
                           const float* __restrict__ Wv,
                           f16* __restrict__ WT) {
    const float* W = (blockIdx.x == 0) ? Wq : (blockIdx.x == 1) ? Wk : Wv;
    f16* o = WT + (size_t)blockIdx.x * (64 * 512);
    for (int i = threadIdx.x; i < 64 * 512; i += blockDim.x) {
        int col = i >> 9, e = i & 511;
        o[i] = (f16)W[e * 64 + col];
    }
}

// ---------------------------------------------------------------------------
// Kernel 1: projection  P = X @ W + b  (X fp32 [32768][512] -> out f16).
// CONTIGUOUS-DMA variant. All prior structures issued 128-256B requests at
// 2KB stride (row-parallel) and pinned at ~2.6 TB/s; m13's 6.3 TB/s streams
// 1KB-contiguous per instruction (HBM page ~1KB: strided sub-page requests
// thrash row-activates). Here each gload16 reads ONE KB of ONE row
// contiguously (src = rowbase + lane*16B). Wave stages 8 whole rows
// (16 gloads); LDS rows padded to 2064B (+16B -> A-frag reads 2-way/free).
// Two phases: issue h0 gloads then h1 -> vmcnt(8)+barrier -> chunks 0-7 ->
// vmcnt(0)+barrier -> chunks 8-15. 2 barriers / 2 waits per block TOTAL.
// Waves split OUTPUT COLS (wave=cf quadrant); W frags direct from L2 (96KB
// hot, R4-validated). BM=32, block 256 (4 waves), LDS 66KB -> 2 blocks/CU.
// grid (1024 row-tiles, 3 tensors).
// tensor 0 -> qp (scaled QSC), 1 -> kp, 2 -> vpT [b][64][4096]
// ---------------------------------------------------------------------------
__global__ __launch_bounds__(256, 2) void ah_proj(
    const float* __restrict__ Xq, const float* __restrict__ Xk, const float* __restrict__ Xv,
    const float* __restrict__ bq, const float* __restrict__ bk, const float* __restrict__ bv,
    const f16* __restrict__ WT,
    f16* __restrict__ qp, f16* __restrict__ kp, f16* __restrict__ vpT) {

    const int tens = blockIdx.y;
    const float* X    = (tens == 0) ? Xq : (tens == 1) ? Xk : Xv;
    const float* bias = (tens == 0) ? bq : (tens == 1) ? bk : bv;
    const f16* wt = WT + (size_t)tens * (64 * 512);
    const float osc = (tens == 0) ? QSC : 1.0f;

    const int lane = threadIdx.x & 63;
    const int wave = threadIdx.x >> 6;           // 0..3 = output-col quadrant
    const int l15 = lane & 15, g = lane >> 4;
    const int row0 = blockIdx.x * 32;

    // X staging: [32 rows][2064B] (2048 data + 16 pad) = 66048 B
    __shared__ __align__(16) char smem[66048];

    // ---- stage: 16 fully-contiguous 1KB gloads per wave (rows wave*8..+7) ----
#pragma unroll
    for (int h = 0; h < 2; ++h)                  // all h0 first, then h1
#pragma unroll
        for (int r = 0; r < 8; ++r)
            gload16(X + (size_t)(row0 + wave * 8 + r) * 512 + h * 256 + lane * 4,
                    smem + (wave * 8 + r) * 2064 + h * 1024);

    f32x4 acc[2];                                // rows rf*16+l15, cols wave*16+l15
#pragma unroll
    for (int rf = 0; rf < 2; ++rf) acc[rf] = (f32x4){0.f, 0.f, 0.f, 0.f};

#define PCHUNK(EC) do {                                                              \
    f16x8 af[2];                                                                     \
    _Pragma("unroll")                                                                \
    for (int rf = 0; rf < 2; ++rf) {                                                 \
        const char* xr = smem + (rf * 16 + l15) * 2064 + (EC) * 128 + g * 32;        \
        float4 v0 = *(const float4*)xr;                                              \
        float4 v1 = *(const float4*)(xr + 16);                                       \
        f16x2 p0 = cvt_pk(v0.x, v0.y), p1 = cvt_pk(v0.z, v0.w);                      \
        f16x2 p2 = cvt_pk(v1.x, v1.y), p3 = cvt_pk(v1.z, v1.w);                      \
        f16x8 a;                                                                     \
        a[0] = p0[0]; a[1] = p0[1]; a[2] = p1[0]; a[3] = p1[1];                      \
        a[4] = p2[0]; a[5] = p2[1]; a[6] = p3[0]; a[7] = p3[1];                      \
        af[rf] = a;                                                                  \
    }                                                                                \
    f16x8 bfr = *(const f16x8*)(wt + (size_t)(wave * 16 + l15) * 512 +               \
                                (EC) * 32 + g * 8);                                  \
    _Pragma("unroll")                                                                \
    for (int rf = 0; rf < 2; ++rf) acc[rf] = mfma16(af[rf], bfr, acc[rf]);           \
} while (0)

    asm volatile("s_waitcnt vmcnt(8)" ::: "memory");   // own h0 gloads done
    __builtin_amdgcn_sched_barrier(0);
    __builtin_amdgcn_s_barrier();                       // all waves' h0 done
    __builtin_amdgcn_sched_barrier(0);
#pragma unroll
    for (int ec = 0; ec < 8; ++ec) PCHUNK(ec);
    asm volatile("s_waitcnt vmcnt(0)" ::: "memory");   // h1 (+ W loads) done
    __builtin_amdgcn_sched_barrier(0);
    __builtin_amdgcn_s_barrier();
    __builtin_amdgcn_sched_barrier(0);
#pragma unroll
    for (int ec = 8; ec < 16; ++ec) PCHUNK(ec);
#undef PCHUNK

    __syncthreads();                              // staging dead; recycle LDS

    // epilogue: bias (+ scale for qp) + f16, stage in recycled LDS [32][68]
    f16* lds = (f16*)smem;
#pragma unroll
    for (int rf = 0; rf < 2; ++rf) {
        float b = bias[wave * 16 + l15];
#pragma unroll
        for (int r = 0; r < 4; ++r) {
            int rr = rf * 16 + g * 4 + r;         // C layout: row=(l>>4)*4+r
            lds[rr * 68 + wave * 16 + l15] = (f16)((acc[rf][r] + b) * osc);
        }
    }
    __syncthreads();

    if (tens < 2) {
        f16* o = ((tens == 0) ? qp : kp) + (size_t)row0 * 64;
        for (int c = threadIdx.x; c < 32 * 16; c += 256) {   // 8B chunks
            int r = c >> 4, ch = c & 15;
            *(f16x4*)(o + r * 64 + ch * 4) = *(const f16x4*)(&lds[r * 68 + ch * 4]);
        }
    } else {
        int b = row0 >> 12, n0 = row0 & 4095;
        f16* o = vpT + (size_t)b * 64 * 4096 + n0;
        for (int c = threadIdx.x; c < 64 * 8; c += 256) {    // 64 d x 8 chunks of 4 n
            int d = c >> 3, nch = c & 7;
            f16x4 v;
#pragma unroll
            for (int j = 0; j < 4; ++j) v[j] = lds[(nch * 4 + j) * 68 + d];
            *(f16x4*)(o + (size_t)d * 4096 + nch * 4) = v;
        }
    }
}

// ---------------------------------------------------------------------------
// Kernel 2: fused flash attention. [R18 verbatim, session best] 4-DEEP
// staging ring, ONE barrier per iteration: vmcnt(8) -> compute(buf i&3) ->
// s_barrier -> stage(buf (i+3)&3). LDS [4 s][4 buf][8KB] = 128KB, 1 block/CU.
// V tile unit-major (conflict-minimal); K XOR-swizzled (validated).
// grid 256: batch = id&7 (XCD-pinned), qtile = id>>3 (128 q-rows).
// block 512 = 8 waves = 2 qg (64 q) x 4 keysplit s (1024 keys, 32 iters of 32).
// ---------------------------------------------------------------------------
__global__ __launch_bounds__(512, 1) void ah_attn(
    const f16* __restrict__ qp, const f16* __restrict__ kp, const f16* __restrict__ vpT,
    const int* __restrict__ maskp, float* __restrict__ out) {

    const int id = blockIdx.x;
    const int batch = id & 7, qtile = id >> 3;
    const int lane = threadIdx.x & 63, wave = threadIdx.x >> 6;
    const int l31 = lane & 31, hi2 = lane >> 5;
    const int s = wave & 3, qg = wave >> 2;
    const int q0 = qtile * 128 + qg * 64;
    const float mthr = L2E * (float)maskp[0];

    const f16* qpb = qp + (size_t)batch * 4096 * 64;
    const f16* kpb = kp + (size_t)batch * 4096 * 64;
    const f16* vpb = vpT + (size_t)batch * 64 * 4096;

    __shared__ __align__(16) char smem[131072];    // [4 s][4 buf][8KB]
    __shared__ float mlx[2][4][2][32];

    const int krow = lane >> 3;                    // 0..7
    const int eswzK = (lane & 7) ^ krow;           // source col16 swizzle (K)
    const int swzK = l31 & 7;                      // read-side XOR (K)

#define STAGE(BUF, IT) do {                                                         \
    const int _k0 = (((IT) * 4 + s) << 5);                                          \
    char* _b = smem + (s * 4 + (BUF)) * 8192 + (qg ? 4096 : 0);                     \
    if (qg == 0) {                                                                  \
        _Pragma("unroll")                                                           \
        for (int _j = 0; _j < 4; ++_j)                                              \
            gload16(kpb + (size_t)(_k0 + _j * 8 + krow) * 64 + eswzK * 8,           \
                    _b + _j * 1024);                                                \
    } else {                                                                        \
        _Pragma("unroll")                                                           \
        for (int _j = 0; _j < 4; ++_j)                                              \
            gload16(vpb + (size_t)(_j * 16 + (lane & 15)) * 4096 + _k0 +            \
                        (lane >> 4) * 8,                                            \
                    _b + _j * 1024);                                                \
    }                                                                               \
} while (0)

    f16x8 qf_[2][4];
#pragma unroll
    for (int qt = 0; qt < 2; ++qt)
#pragma unroll
        for (int st = 0; st < 4; ++st)
            qf_[qt][st] = *(const f16x8*)(qpb + (size_t)(q0 + qt * 32 + l31) * 64 + st * 16 + hi2 * 8);

    f32x16 oacc[2][2];
#pragma unroll
    for (int dt = 0; dt < 2; ++dt)
#pragma unroll
        for (int qt = 0; qt < 2; ++qt)
#pragma unroll
            for (int r = 0; r < 16; ++r) oacc[dt][qt][r] = 0.f;
    float ps[2] = {0.f, 0.f};

    STAGE(0, 0); STAGE(1, 1); STAGE(2, 2);
    __builtin_amdgcn_s_barrier();                 // stages issued before loop
    for (int it = 0; it < 32; ++it) {
        if (it < 30)      asm volatile("s_waitcnt vmcnt(8)" ::: "memory");
        else if (it == 30) asm volatile("s_waitcnt vmcnt(4)" ::: "memory");
        else              asm volatile("s_waitcnt vmcnt(0)" ::: "memory");
        __builtin_amdgcn_sched_barrier(0);

        const char* kb = smem + (s * 4 + (it & 3)) * 8192;
        const char* vb = kb + 4096;

        // ---- K frags + QK^T ----
        f16x8 ka[4];
#pragma unroll
        for (int st = 0; st < 4; ++st)
            ka[st] = *(const f16x8*)(kb + l31 * 128 + (((st * 2 + hi2) ^ swzK) << 4));
        f32x16 sacc[2];
#pragma unroll
        for (int qt = 0; qt < 2; ++qt)
#pragma unroll
            for (int r = 0; r < 16; ++r) sacc[qt][r] = 0.f;
#pragma unroll
        for (int st = 0; st < 4; ++st)
#pragma unroll
            for (int qt = 0; qt < 2; ++qt)
                sacc[qt] = mfma32(ka[st], qf_[qt][st], sacc[qt]);

        // ---- V frags (unit-major layout) ----
        f16x8 av[2][2];
#pragma unroll
        for (int dt = 0; dt < 2; ++dt) {
            const char* vchunk = vb + (dt * 2 + (l31 >> 4)) * 1024 + (l31 & 15) * 16 + hi2 * 8;
#pragma unroll
            for (int t = 0; t < 2; ++t) {
                *(f16x4*)(&av[dt][t])       = *(const f16x4*)(vchunk + (t * 2 + 0) * 256);
                *((f16x4*)(&av[dt][t]) + 1) = *(const f16x4*)(vchunk + (t * 2 + 1) * 256);
            }
        }

        // ---- fixed-max softmax: p = exp2(sacc), pack pairs -> PV B-frags ----
        f16x8 pb_[2][2];
#pragma unroll
        for (int qt = 0; qt < 2; ++qt)
#pragma unroll
            for (int t = 0; t < 2; ++t)
#pragma unroll
                for (int w = 0; w < 4; ++w) {
                    float s0 = sacc[qt][t * 8 + 2 * w];
                    float s1 = sacc[qt][t * 8 + 2 * w + 1];
                    float e0 = __builtin_amdgcn_exp2f(s0);
                    float e1 = __builtin_amdgcn_exp2f(s1);
                    float p0 = (s0 == mthr) ? 0.f : e0;
                    float p1 = (s1 == mthr) ? 0.f : e1;
                    ps[qt] += p0 + p1;
                    ((f16x2*)(&pb_[qt][t]))[w] = cvt_pk(p0, p1);
                }

        // ---- PV ----
#pragma unroll
        for (int dt = 0; dt < 2; ++dt)
#pragma unroll
            for (int qt = 0; qt < 2; ++qt)
#pragma unroll
                for (int t = 0; t < 2; ++t)
                    oacc[dt][qt] = mfma32(av[dt][t], pb_[qt][t], oacc[dt][qt]);

        __builtin_amdgcn_sched_barrier(0);
        __builtin_amdgcn_s_barrier();             // all waves done with buf (it-1)&3
        __builtin_amdgcn_sched_barrier(0);
        if (it < 29) STAGE((it + 3) & 3, it + 3); // overwrite is now safe
    }
#undef STAGE

    // ---- epilogue: Sum(p) exchange + 4-way tree combine in recycled LDS ----
    ps[0] += __shfl_xor(ps[0], 32);
    ps[1] += __shfl_xor(ps[1], 32);
    if (lane < 32) { mlx[qg][s][0][lane] = ps[0]; mlx[qg][s][1][lane] = ps[1]; }
    __syncthreads();

    float* SC = (float*)smem;        // [qg*2+b][64 regs][64 lanes]
#define SCI(B, DT, QT, R) ((((qg * 2 + (B)) * 64) + ((DT) * 2 + (QT)) * 16 + (R)) * 64 + lane)
    if (s >= 2) {
#pragma unroll
        for (int dt = 0; dt < 2; ++dt)
#pragma unroll
            for (int qt = 0; qt < 2; ++qt)
#pragma unroll
                for (int r = 0; r < 16; ++r)
                    SC[SCI(s - 2, dt, qt, r)] = oacc[dt][qt][r];
    }
    __syncthreads();
    if (s < 2) {
#pragma unroll
        for (int dt = 0; dt < 2; ++dt)
#pragma unroll
            for (int qt = 0; qt < 2; ++qt)
#pragma unroll
                for (int r = 0; r < 16; ++r)
                    oacc[dt][qt][r] += SC[SCI(s, dt, qt, r)];
        if (s == 1) {
#pragma unroll
            for (int dt = 0; dt < 2; ++dt)
#pragma unroll
                for (int qt = 0; qt < 2; ++qt)
#pragma unroll
                    for (int r = 0; r < 16; ++r)
                        SC[SCI(1, dt, qt, r)] = oacc[dt][qt][r];
        }
    }
    __syncthreads();
    if (s == 0) {
        float inv[2];
#pragma unroll
        for (int qt = 0; qt < 2; ++qt)
            inv[qt] = 1.0f / (mlx[qg][0][qt][l31] + mlx[qg][1][qt][l31] +
                              mlx[qg][2][qt][l31] + mlx[qg][3][qt][l31]);
#pragma unroll
        for (int qt = 0; qt < 2; ++qt) {
            float* o0 = out + ((size_t)batch * 4096 + q0 + qt * 32 + l31) * 64;
#pragma unroll
            for (int dt = 0; dt < 2; ++dt)
#pragma unroll
                for (int rg = 0; rg < 4; ++rg) {  // reg r=rg*4+j -> d = dt*32+rg*8+hi*4+j
                    float4 v;
                    v.x = (oacc[dt][qt][rg * 4 + 0] + SC[SCI(1, dt, qt, rg * 4 + 0)]) * inv[qt];
                    v.y = (oacc[dt][qt][rg * 4 + 1] + SC[SCI(1, dt, qt, rg * 4 + 1)]) * inv[qt];
                    v.z = (oacc[dt][qt][rg * 4 + 2] + SC[SCI(1, dt, qt, rg * 4 + 2)]) * inv[qt];
                    v.w = (oacc[dt][qt][rg * 4 + 3] + SC[SCI(1, dt, qt, rg * 4 + 3)]) * inv[qt];
                    *(float4*)(o0 + dt * 32 + rg * 8 + hi2 * 4) = v;
                }
        }
    }
#undef SCI
}

// ---------------------------------------------------------------------------
extern "C" void kernel_launch(void* const* d_in, const int* in_sizes, int n_in,
                              void* d_out, int out_size, void* d_ws, size_t ws_size,
                              hipStream_t stream) {
    const float* q  = (const float*)d_in[0];
    const float* k  = (const float*)d_in[1];
    const float* v  = (const float*)d_in[2];
    const float* Wq = (const float*)d_in[3];
    const float* bq = (const float*)d_in[4];
    const float* Wk = (const float*)d_in[5];
    const float* bk = (const float*)d_in[6];
    const float* Wv = (const float*)d_in[7];
    const float* bv = (const float*)d_in[8];
    const int* mask = (const int*)d_in[9];
    float* out = (float*)d_out;

    const size_t NTOK = (size_t)8 * 4096;      // 32768 rows
    f16* qp  = (f16*)d_ws;                     // [8][4096][64]  (pre-scaled by QSC)
    f16* kp  = qp + NTOK * 64;                 // [8][4096][64]
    f16* vpT = kp + NTOK * 64;                 // [8][64][4096]
    f16* WT  = vpT + NTOK * 64;                // [3][64][512]

    ah_wt_prep<<<dim3(3), 256, 0, stream>>>(Wq, Wk, Wv, WT);
    ah_proj<<<dim3(1024, 3), 256, 0, stream>>>(q, k, v, bq, bk, bv, WT, qp, kp, vpT);
    ah_attn<<<dim3(256), 512, 0, stream>>>(qp, kp, vpT, mask, out);
}

// Round 21
// 115.466 us; speedup vs baseline: 1.2973x; 1.0655x over previous
//
#include <hip/hip_runtime.h>

typedef _Float16 f16;
typedef _Float16 f16x2 __attribute__((ext_vector_type(2)));
typedef _Float16 f16x4 __attribute__((ext_vector_type(4)));
typedef _Float16 f16x8 __attribute__((ext_vector_type(8)));
typedef __fp16   h16x2 __attribute__((ext_vector_type(2)));
typedef float    f32x4 __attribute__((ext_vector_type(4)));
typedef float    f32x16 __attribute__((ext_vector_type(16)));

static constexpr float L2E = 1.44269504088896340736f;
// folded into q-projection: (1/sqrt(64)) * log2(e)
static constexpr float QSC = 0.18033688011112042f;

static __device__ __forceinline__ f32x4 mfma16(f16x8 a, f16x8 b, f32x4 c) {
    return __builtin_amdgcn_mfma_f32_16x16x32_f16(a, b, c, 0, 0, 0);
}
static __device__ __forceinline__ f32x16 mfma32(f16x8 a, f16x8 b, f32x16 c) {
    return __builtin_amdgcn_mfma_f32_32x32x16_f16(a, b, c, 0, 0, 0);
}
static __device__ __forceinline__ f16x2 cvt_pk(float a, float b) {
    h16x2 t = __builtin_amdgcn_cvt_pkrtz(a, b);
    return __builtin_bit_cast(f16x2, t);
}
// async global->LDS DMA, 16B per lane. LDS dest = WAVE-UNIFORM base + lane*16.
static __device__ __forceinline__ void gload16(const void* g, void* l) {
    __builtin_amdgcn_global_load_lds(
        (const __attribute__((address_space(1))) unsigned int*)g,
        (__attribute__((address_space(3))) unsigned int*)l, 16, 0, 0);
}

// ---------------------------------------------------------------------------
// Kernel 0: transpose W [512][64] f32 -> WT [64][512] f16 (per tensor)
// ---------------------------------------------------------------------------
__global__ void ah_wt_prep(const float* __restrict__ Wq,
                           const float* __restrict__ Wk,
                           const float* __restrict__ Wv,
                           f16* __restrict__ WT) {
    const float* W = (blockIdx.x == 0) ? Wq : (blockIdx.x == 1) ? Wk : Wv;
    f16* o = WT + (size_t)blockIdx.x * (64 * 512);
    for (int i = threadIdx.x; i < 64 * 512; i += blockDim.x) {
        int col = i >> 9, e = i & 511;
        o[i] = (f16)W[e * 64 + col];
    }
}

// ---------------------------------------------------------------------------
// Kernel 1: projection  P = X @ W + b  (X fp32 [32768][512] -> out f16).
// R13 verbatim (best measured): DMA barrier-pipeline, DEPTH-3, BK=32,
// 4 buffers x (X 8KB + W 4KB) = 48KB LDS -> 3 blocks/CU. vmcnt(9) steady,
// drain 6/3/0. X XOR-swizzled (unit^=row&7, source-pre-swizzled); W linear.
// grid (512 row-tiles of 64, 3 tensors), block 256 = 4 waves x 16 rows.
// tensor 0 -> qp (scaled QSC), 1 -> kp, 2 -> vpT [b][64][4096]
// ---------------------------------------------------------------------------
__global__ __launch_bounds__(256, 3) void ah_proj(
    const float* __restrict__ Xq, const float* __restrict__ Xk, const float* __restrict__ Xv,
    const float* __restrict__ bq, const float* __restrict__ bk, const float* __restrict__ bv,
    const f16* __restrict__ WT,
    f16* __restrict__ qp, f16* __restrict__ kp, f16* __restrict__ vpT) {

    const int tens = blockIdx.y;
    const float* X    = (tens == 0) ? Xq : (tens == 1) ? Xk : Xv;
    const float* bias = (tens == 0) ? bq : (tens == 1) ? bk : bv;
    const f16* wt = WT + (size_t)tens * (64 * 512);
    const float osc = (tens == 0) ? QSC : 1.0f;

    const int lane = threadIdx.x & 63;
    const int wave = threadIdx.x >> 6;
    const int l15 = lane & 15, g = lane >> 4;
    const int row0 = blockIdx.x * 64;
    const int wrow = wave * 16;

    __shared__ __align__(16) char smem[49152];   // 4 x (X 8KB | W 4KB)

    const int xr8 = lane >> 3;                   // 0..7
    const int xsu = (lane & 7) ^ xr8;            // source unit (pre-swizzled)

#define PSTAGE(KC) do {                                                              \
    char* _xb = smem + ((KC) & 3) * 12288;                                           \
    char* _wb = _xb + 8192;                                                          \
    gload16(X + (size_t)(row0 + wrow + xr8) * 512 + (KC) * 32 + xsu * 4,             \
            _xb + wave * 2048);                                                      \
    gload16(X + (size_t)(row0 + wrow + 8 + xr8) * 512 + (KC) * 32 + xsu * 4,         \
            _xb + wave * 2048 + 1024);                                               \
    gload16(wt + (size_t)(wrow + (lane >> 2)) * 512 + (KC) * 32 + (lane & 3) * 8,    \
            _wb + wave * 1024);                                                      \
} while (0)

    f32x4 acc[4];
#pragma unroll
    for (int b = 0; b < 4; ++b) acc[b] = (f32x4){0.f, 0.f, 0.f, 0.f};

#define PCOMP(KC) do {                                                               \
    const char* _xb = smem + ((KC) & 3) * 12288;                                     \
    const char* _wb = _xb + 8192;                                                    \
    const char* _cb = _xb + (wrow + l15) * 128;                                      \
    float4 v0 = *(const float4*)(_cb + (((2 * g + 0) ^ (l15 & 7)) << 4));            \
    float4 v1 = *(const float4*)(_cb + (((2 * g + 1) ^ (l15 & 7)) << 4));            \
    f16x2 p0 = cvt_pk(v0.x, v0.y), p1 = cvt_pk(v0.z, v0.w);                          \
    f16x2 p2 = cvt_pk(v1.x, v1.y), p3 = cvt_pk(v1.z, v1.w);                          \
    f16x8 a;                                                                         \
    a[0] = p0[0]; a[1] = p0[1]; a[2] = p1[0]; a[3] = p1[1];                          \
    a[4] = p2[0]; a[5] = p2[1]; a[6] = p3[0]; a[7] = p3[1];                          \
    _Pragma("unroll")                                                                \
    for (int cf = 0; cf < 4; ++cf) {                                                 \
        f16x8 bfr = *(const f16x8*)(_wb + (cf * 16 + l15) * 64 + g * 16);            \
        acc[cf] = mfma16(a, bfr, acc[cf]);                                           \
    }                                                                                \
} while (0)

    PSTAGE(0); PSTAGE(1); PSTAGE(2);
    for (int kc = 0; kc < 13; ++kc) {            // steady state: depth-3
        PSTAGE(kc + 3);
        asm volatile("s_waitcnt vmcnt(9)" ::: "memory");
        __builtin_amdgcn_sched_barrier(0);
        __builtin_amdgcn_s_barrier();
        __builtin_amdgcn_sched_barrier(0);
        PCOMP(kc);
        __builtin_amdgcn_sched_barrier(0);
        __builtin_amdgcn_s_barrier();
    }
    // drain: chunks 13,14,15
    asm volatile("s_waitcnt vmcnt(6)" ::: "memory");
    __builtin_amdgcn_sched_barrier(0);
    __builtin_amdgcn_s_barrier();
    PCOMP(13);
    __builtin_amdgcn_s_barrier();
    asm volatile("s_waitcnt vmcnt(3)" ::: "memory");
    __builtin_amdgcn_sched_barrier(0);
    __builtin_amdgcn_s_barrier();
    PCOMP(14);
    __builtin_amdgcn_s_barrier();
    asm volatile("s_waitcnt vmcnt(0)" ::: "memory");
    __builtin_amdgcn_sched_barrier(0);
    __builtin_amdgcn_s_barrier();
    PCOMP(15);
    __syncthreads();
#undef PSTAGE
#undef PCOMP

    // epilogue: bias (+ scale for qp) + f16, stage in recycled LDS [64][68]
    f16* lds = (f16*)smem;
#pragma unroll
    for (int cf = 0; cf < 4; ++cf) {
        float b = bias[cf * 16 + l15];
#pragma unroll
        for (int r = 0; r < 4; ++r) {
            int rr = wrow + g * 4 + r;            // C layout: row=(l>>4)*4+r
            lds[rr * 68 + cf * 16 + l15] = (f16)((acc[cf][r] + b) * osc);
        }
    }
    __syncthreads();

    if (tens < 2) {
        f16* o = ((tens == 0) ? qp : kp) + (size_t)row0 * 64;
        for (int c = threadIdx.x; c < 64 * 16; c += 256) {   // 8B chunks
            int r = c >> 4, ch = c & 15;
            *(f16x4*)(o + r * 64 + ch * 4) = *(const f16x4*)(&lds[r * 68 + ch * 4]);
        }
    } else {
        int b = row0 >> 12, n0 = row0 & 4095;
        f16* o = vpT + (size_t)b * 64 * 4096 + n0;
        for (int c = threadIdx.x; c < 64 * 16; c += 256) {   // 64 d x 16 chunks of 4 n
            int d = c >> 4, nch = c & 15;
            f16x4 v;
#pragma unroll
            for (int j = 0; j < 4; ++j) v[j] = lds[(nch * 4 + j) * 68 + d];
            *(f16x4*)(o + (size_t)d * 4096 + nch * 4) = v;
        }
    }
}

// ---------------------------------------------------------------------------
// Kernel 2: fused flash attention. [R18 verbatim, session best] 4-DEEP
// staging ring, ONE barrier per iteration: vmcnt(8) -> compute(buf i&3) ->
// s_barrier -> stage(buf (i+3)&3). LDS [4 s][4 buf][8KB] = 128KB, 1 block/CU.
// V tile unit-major (conflict-minimal); K XOR-swizzled (validated).
// grid 256: batch = id&7 (XCD-pinned), qtile = id>>3 (128 q-rows).
// block 512 = 8 waves = 2 qg (64 q) x 4 keysplit s (1024 keys, 32 iters of 32).
// ---------------------------------------------------------------------------
__global__ __launch_bounds__(512, 1) void ah_attn(
    const f16* __restrict__ qp, const f16* __restrict__ kp, const f16* __restrict__ vpT,
    const int* __restrict__ maskp, float* __restrict__ out) {

    const int id = blockIdx.x;
    const int batch = id & 7, qtile = id >> 3;
    const int lane = threadIdx.x & 63, wave = threadIdx.x >> 6;
    const int l31 = lane & 31, hi2 = lane >> 5;
    const int s = wave & 3, qg = wave >> 2;
    const int q0 = qtile * 128 + qg * 64;
    const float mthr = L2E * (float)maskp[0];

    const f16* qpb = qp + (size_t)batch * 4096 * 64;
    const f16* kpb = kp + (size_t)batch * 4096 * 64;
    const f16* vpb = vpT + (size_t)batch * 64 * 4096;

    __shared__ __align__(16) char smem[131072];    // [4 s][4 buf][8KB]
    __shared__ float mlx[2][4][2][32];

    const int krow = lane >> 3;                    // 0..7
    const int eswzK = (lane & 7) ^ krow;           // source col16 swizzle (K)
    const int swzK = l31 & 7;                      // read-side XOR (K)

#define STAGE(BUF, IT) do {                                                         \
    const int _k0 = (((IT) * 4 + s) << 5);                                          \
    char* _b = smem + (s * 4 + (BUF)) * 8192 + (qg ? 4096 : 0);                     \
    if (qg == 0) {                                                                  \
        _Pragma("unroll")                                                           \
        for (int _j = 0; _j < 4; ++_j)                                              \
            gload16(kpb + (size_t)(_k0 + _j * 8 + krow) * 64 + eswzK * 8,           \
                    _b + _j * 1024);                                                \
    } else {                                                                        \
        _Pragma("unroll")                                                           \
        for (int _j = 0; _j < 4; ++_j)                                              \
            gload16(vpb + (size_t)(_j * 16 + (lane & 15)) * 4096 + _k0 +            \
                        (lane >> 4) * 8,                                            \
                    _b + _j * 1024);                                                \
    }                                                                               \
} while (0)

    f16x8 qf_[2][4];
#pragma unroll
    for (int qt = 0; qt < 2; ++qt)
#pragma unroll
        for (int st = 0; st < 4; ++st)
            qf_[qt][st] = *(const f16x8*)(qpb + (size_t)(q0 + qt * 32 + l31) * 64 + st * 16 + hi2 * 8);

    f32x16 oacc[2][2];
#pragma unroll
    for (int dt = 0; dt < 2; ++dt)
#pragma unroll
        for (int qt = 0; qt < 2; ++qt)
#pragma unroll
            for (int r = 0; r < 16; ++r) oacc[dt][qt][r] = 0.f;
    float ps[2] = {0.f, 0.f};

    STAGE(0, 0); STAGE(1, 1); STAGE(2, 2);
    __builtin_amdgcn_s_barrier();                 // stages issued before loop
    for (int it = 0; it < 32; ++it) {
        if (it < 30)      asm volatile("s_waitcnt vmcnt(8)" ::: "memory");
        else if (it == 30) asm volatile("s_waitcnt vmcnt(4)" ::: "memory");
        else              asm volatile("s_waitcnt vmcnt(0)" ::: "memory");
        __builtin_amdgcn_sched_barrier(0);

        const char* kb = smem + (s * 4 + (it & 3)) * 8192;
        const char* vb = kb + 4096;

        // ---- K frags + QK^T ----
        f16x8 ka[4];
#pragma unroll
        for (int st = 0; st < 4; ++st)
            ka[st] = *(const f16x8*)(kb + l31 * 128 + (((st * 2 + hi2) ^ swzK) << 4));
        f32x16 sacc[2];
#pragma unroll
        for (int qt = 0; qt < 2; ++qt)
#pragma unroll
            for (int r = 0; r < 16; ++r) sacc[qt][r] = 0.f;
#pragma unroll
        for (int st = 0; st < 4; ++st)
#pragma unroll
            for (int qt = 0; qt < 2; ++qt)
                sacc[qt] = mfma32(ka[st], qf_[qt][st], sacc[qt]);

        // ---- V frags (unit-major layout) ----
        f16x8 av[2][2];
#pragma unroll
        for (int dt = 0; dt < 2; ++dt) {
            const char* vchunk = vb + (dt * 2 + (l31 >> 4)) * 1024 + (l31 & 15) * 16 + hi2 * 8;
#pragma unroll
            for (int t = 0; t < 2; ++t) {
                *(f16x4*)(&av[dt][t])       = *(const f16x4*)(vchunk + (t * 2 + 0) * 256);
                *((f16x4*)(&av[dt][t]) + 1) = *(const f16x4*)(vchunk + (t * 2 + 1) * 256);
            }
        }

        // ---- fixed-max softmax: p = exp2(sacc), pack pairs -> PV B-frags ----
        f16x8 pb_[2][2];
#pragma unroll
        for (int qt = 0; qt < 2; ++qt)
#pragma unroll
            for (int t = 0; t < 2; ++t)
#pragma unroll
                for (int w = 0; w < 4; ++w) {
                    float s0 = sacc[qt][t * 8 + 2 * w];
                    float s1 = sacc[qt][t * 8 + 2 * w + 1];
                    float e0 = __builtin_amdgcn_exp2f(s0);
                    float e1 = __builtin_amdgcn_exp2f(s1);
                    float p0 = (s0 == mthr) ? 0.f : e0;
                    float p1 = (s1 == mthr) ? 0.f : e1;
                    ps[qt] += p0 + p1;
                    ((f16x2*)(&pb_[qt][t]))[w] = cvt_pk(p0, p1);
                }

        // ---- PV ----
#pragma unroll
        for (int dt = 0; dt < 2; ++dt)
#pragma unroll
            for (int qt = 0; qt < 2; ++qt)
#pragma unroll
                for (int t = 0; t < 2; ++t)
                    oacc[dt][qt] = mfma32(av[dt][t], pb_[qt][t], oacc[dt][qt]);

        __builtin_amdgcn_sched_barrier(0);
        __builtin_amdgcn_s_barrier();             // all waves done with buf (it-1)&3
        __builtin_amdgcn_sched_barrier(0);
        if (it < 29) STAGE((it + 3) & 3, it + 3); // overwrite is now safe
    }
#undef STAGE

    // ---- epilogue: Sum(p) exchange + 4-way tree combine in recycled LDS ----
    ps[0] += __shfl_xor(ps[0], 32);
    ps[1] += __shfl_xor(ps[1], 32);
    if (lane < 32) { mlx[qg][s][0][lane] = ps[0]; mlx[qg][s][1][lane] = ps[1]; }
    __syncthreads();

    float* SC = (float*)smem;        // [qg*2+b][64 regs][64 lanes]
#define SCI(B, DT, QT, R) ((((qg * 2 + (B)) * 64) + ((DT) * 2 + (QT)) * 16 + (R)) * 64 + lane)
    if (s >= 2) {
#pragma unroll
        for (int dt = 0; dt < 2; ++dt)
#pragma unroll
            for (int qt = 0; qt < 2; ++qt)
#pragma unroll
                for (int r = 0; r < 16; ++r)
                    SC[SCI(s - 2, dt, qt, r)] = oacc[dt][qt][r];
    }
    __syncthreads();
    if (s < 2) {
#pragma unroll
        for (int dt = 0; dt < 2; ++dt)
#pragma unroll
            for (int qt = 0; qt < 2; ++qt)
#pragma unroll
                for (int r = 0; r < 16; ++r)
                    oacc[dt][qt][r] += SC[SCI(s, dt, qt, r)];
        if (s == 1) {
#pragma unroll
            for (int dt = 0; dt < 2; ++dt)
#pragma unroll
                for (int qt = 0; qt < 2; ++qt)
#pragma unroll
                    for (int r = 0; r < 16; ++r)
                        SC[SCI(1, dt, qt, r)] = oacc[dt][qt][r];
        }
    }
    __syncthreads();
    if (s == 0) {
        float inv[2];
#pragma unroll
        for (int qt = 0; qt < 2; ++qt)
            inv[qt] = 1.0f / (mlx[qg][0][qt][l31] + mlx[qg][1][qt][l31] +
                              mlx[qg][2][qt][l31] + mlx[qg][3][qt][l31]);
#pragma unroll
        for (int qt = 0; qt < 2; ++qt) {
            float* o0 = out + ((size_t)batch * 4096 + q0 + qt * 32 + l31) * 64;
#pragma unroll
            for (int dt = 0; dt < 2; ++dt)
#pragma unroll
                for (int rg = 0; rg < 4; ++rg) {  // reg r=rg*4+j -> d = dt*32+rg*8+hi*4+j
                    float4 v;
                    v.x = (oacc[dt][qt][rg * 4 + 0] + SC[SCI(1, dt, qt, rg * 4 + 0)]) * inv[qt];
                    v.y = (oacc[dt][qt][rg * 4 + 1] + SC[SCI(1, dt, qt, rg * 4 + 1)]) * inv[qt];
                    v.z = (oacc[dt][qt][rg * 4 + 2] + SC[SCI(1, dt, qt, rg * 4 + 2)]) * inv[qt];
                    v.w = (oacc[dt][qt][rg * 4 + 3] + SC[SCI(1, dt, qt, rg * 4 + 3)]) * inv[qt];
                    *(float4*)(o0 + dt * 32 + rg * 8 + hi2 * 4) = v;
                }
        }
    }
#undef SCI
}

// ---------------------------------------------------------------------------
extern "C" void kernel_launch(void* const* d_in, const int* in_sizes, int n_in,
                              void* d_out, int out_size, void* d_ws, size_t ws_size,
                              hipStream_t stream) {
    const float* q  = (const float*)d_in[0];
    const float* k  = (const float*)d_in[1];
    const float* v  = (const float*)d_in[2];
    const float* Wq = (const float*)d_in[3];
    const float* bq = (const float*)d_in[4];
    const float* Wk = (const float*)d_in[5];
    const float* bk = (const float*)d_in[6];
    const float* Wv = (const float*)d_in[7];
    const float* bv = (const float*)d_in[8];
    const int* mask = (const int*)d_in[9];
    float* out = (float*)d_out;

    const size_t NTOK = (size_t)8 * 4096;      // 32768 rows
    f16* qp  = (f16*)d_ws;                     // [8][4096][64]  (pre-scaled by QSC)
    f16* kp  = qp + NTOK * 64;                 // [8][4096][64]
    f16* vpT = kp + NTOK * 64;                 // [8][64][4096]
    f16* WT  = vpT + NTOK * 64;                // [3][64][512]

    ah_wt_prep<<<dim3(3), 256, 0, stream>>>(Wq, Wk, Wv, WT);
    ah_proj<<<dim3(512, 3), 256, 0, stream>>>(q, k, v, bq, bk, bv, WT, qp, kp, vpT);
    ah_attn<<<dim3(256), 512, 0, stream>>>(qp, kp, vpT, mask, out);
}